// Round 12
// baseline (115.279 us; speedup 1.0000x reference)
//
#include <hip/hip_runtime.h>

typedef unsigned short u16;
typedef unsigned int   u32;

typedef __bf16 bf16x8 __attribute__((ext_vector_type(8)));
typedef float  f32x4  __attribute__((ext_vector_type(4)));

#define B_DIM 4
#define T_DIM 8192
#define D_DIM 512
#define M_DIM (B_DIM * T_DIM)   // 32768
#define K_DIM D_DIM             // 512
#define NC    256               // chunks along T
#define LCH   32                // chunk length (NC*LCH == T_DIM)

__device__ __forceinline__ u16 f2bf(float f) {
  u32 u = __float_as_uint(f);
  u32 r = (u + 0x7FFFu + ((u >> 16) & 1u)) >> 16;   // RNE
  return (u16)r;
}
__device__ __forceinline__ float bf2f(u16 b) {
  return __uint_as_float(((u32)b) << 16);
}

// async global->LDS, 16B per lane; lds dest is wave-uniform base + lane*16
__device__ __forceinline__ void gload_lds16(const u16* g, u16* lds) {
  __builtin_amdgcn_global_load_lds(
      (const __attribute__((address_space(1))) void*)g,
      (__attribute__((address_space(3))) void*)lds, 16, 0, 0);
}

// ---------------- conversion kernels ----------------

__global__ void convert_x(const float4* __restrict__ in, u16* __restrict__ out, int n4) {
  int i = blockIdx.x * blockDim.x + threadIdx.x;
  int stride = gridDim.x * blockDim.x;
  for (; i < n4; i += stride) {
    float4 f = in[i];
    u32 w0 = (u32)f2bf(f.x) | ((u32)f2bf(f.y) << 16);
    u32 w1 = (u32)f2bf(f.z) | ((u32)f2bf(f.w) << 16);
    *reinterpret_cast<uint2*>(out + (size_t)i * 4) = make_uint2(w0, w1);
  }
}

// W [K=512][N=1024] fp32 -> wt [N=1024][K=512] bf16 (transposed)
__global__ void convert_wt(const float* __restrict__ W, u16* __restrict__ wt) {
  int idx = blockIdx.x * blockDim.x + threadIdx.x;  // 65536 threads
  int n  = idx & 1023;
  int k0 = (idx >> 10) * 8;
  float f[8];
#pragma unroll
  for (int j = 0; j < 8; ++j) f[j] = W[(size_t)(k0 + j) * 1024 + n];
  u32 w[4];
#pragma unroll
  for (int j = 0; j < 4; ++j)
    w[j] = (u32)f2bf(f[2 * j]) | ((u32)f2bf(f[2 * j + 1]) << 16);
  *reinterpret_cast<uint4*>(wt + (size_t)n * 512 + k0) = make_uint4(w[0], w[1], w[2], w[3]);
}

// ---- GEMM: 256Mx256N, 8 waves (2wr x 4wc), wave 128x64, acc[8][4], BK=32 ----
// Round-9 3-buf rolling counted-vmcnt schedule (proven), bigger wave tile:
// LDS-bytes/MFMA 256 -> 192.  Iter t: s_waitcnt vmcnt(4) [tile t's 4 loads
// done; t+1's in flight] -> s_barrier -> STAGE(t+2) -> COMPUTE(t).  Stage t+2
// overwrites buf computed at t-1; this iter's barrier orders it.
// LDS per buf: A 256x32 (16KB) + B 256x32 (16KB); 3 bufs = 96KB, 1 block/CU.
// Swizzle: slot_phys = slot_log^(pair&7), staged via inverse-swizzled GLOBAL
// source (rule #21; proven 0 conflicts).
// B tile rows j (0..255): p=j>>5: gn = (p&1)*512 + d0 + (p>>1)*32 + (j&31)
// -> wave wc cols 64wc+16n+l15: hidden=acc[m][n], gate=acc[m][n+2] (n<2),
// channel dch = d0 + 32*wc + 16n + l15, d0 = blockIdx.y*128.

#define BK 32
#define NT 16

__global__ __launch_bounds__(512, 2) void gemm_act(const u16* __restrict__ xb,
                                                   const u16* __restrict__ wt,
                                                   u32* __restrict__ av_buf,
                                                   float* __restrict__ Asum,
                                                   float* __restrict__ Bsum) {
  __shared__ u16 As[3][8192];   // 3 x 16 KB (256 rows x 32 k)
  __shared__ u16 Bs[3][8192];   // 3 x 16 KB (256 rows x 32 k)

  const int tid  = threadIdx.x;
  const int lane = tid & 63;
  const int wave = tid >> 6;        // 0..7
  const int l15  = lane & 15;
  const int lh   = lane >> 4;       // 0..3
  const int wr   = wave >> 2;       // 0..1  (row half: 128 rows)
  const int wc   = wave & 3;        // 0..3  (col quarter: 64 cols)
  const int m_base = blockIdx.x * 256;
  const int d0     = blockIdx.y * 128;

  // staging: thread tid -> linear 16B slot tid within a 128-row call region
  const int pairl = tid >> 3;                   // 0..63
  const int slog  = (tid & 7) ^ (pairl & 7);    // logical slot
  const int lrow  = (pairl << 1) | (slog >> 2); // 0..127
  const int scol  = (slog & 3) << 3;            // k elem offset 0/8/16/24
  const int garow0 = m_base + lrow;             // A call 0: rows 0..127
  const int garow1 = garow0 + 128;              // A call 1: rows 128..255
  const int pB = lrow >> 5;                     // B call 0: j = lrow
  const int gn0 = ((pB & 1) ? 512 : 0) + d0 + ((pB >> 1) << 5) + (lrow & 31);
  const int gn1 = gn0 + 64;                     // B call 1: j = 128 + lrow
  const int ldsw = wave * 512;                  // wave's 1KB within a call

  f32x4 acc[8][4];
#pragma unroll
  for (int m = 0; m < 8; ++m)
#pragma unroll
    for (int n = 0; n < 4; ++n)
      acc[m][n] = (f32x4){0.f, 0.f, 0.f, 0.f};

#define STAGE(buf, kt)                                                      \
  do {                                                                      \
    const int ko = (kt) * BK + scol;                                        \
    gload_lds16(xb + (size_t)garow0 * K_DIM + ko, &As[buf][ldsw]);          \
    gload_lds16(xb + (size_t)garow1 * K_DIM + ko, &As[buf][4096 + ldsw]);   \
    gload_lds16(wt + (size_t)gn0 * K_DIM + ko, &Bs[buf][ldsw]);             \
    gload_lds16(wt + (size_t)gn1 * K_DIM + ko, &Bs[buf][4096 + ldsw]);      \
  } while (0)

  // swizzled read offset (elems) for logical (row, k-chunk lh)
#define AOFF(row) (((row) >> 1) * 64 + (((((((row) & 1) << 2) | lh)) ^ (((row) >> 1) & 7)) << 3))

#define COMPUTE(cur)                                                        \
  do {                                                                      \
    bf16x8 bfr[4];                                                          \
    _Pragma("unroll")                                                       \
    for (int n = 0; n < 4; ++n)                                             \
      bfr[n] = *reinterpret_cast<const bf16x8*>(&Bs[cur][AOFF(64 * wc + 16 * n + l15)]); \
    _Pragma("unroll")                                                       \
    for (int mh = 0; mh < 2; ++mh) {                                        \
      bf16x8 af[4];                                                         \
      _Pragma("unroll")                                                     \
      for (int mm = 0; mm < 4; ++mm)                                        \
        af[mm] = *reinterpret_cast<const bf16x8*>(&As[cur][AOFF(128 * wr + 64 * mh + 16 * mm + l15)]); \
      __builtin_amdgcn_s_setprio(1);                                        \
      _Pragma("unroll")                                                     \
      for (int mm = 0; mm < 4; ++mm)                                        \
        _Pragma("unroll")                                                   \
        for (int n = 0; n < 4; ++n)                                         \
          acc[4 * mh + mm][n] = __builtin_amdgcn_mfma_f32_16x16x32_bf16(af[mm], bfr[n], acc[4 * mh + mm][n], 0, 0, 0); \
      __builtin_amdgcn_s_setprio(0);                                        \
    }                                                                       \
  } while (0)

#define WAITV(N) asm volatile("s_waitcnt vmcnt(" #N ")" ::: "memory")
#define BAR()    asm volatile("s_barrier" ::: "memory")

  STAGE(0, 0);
  STAGE(1, 1);
#pragma unroll
  for (int t = 0; t < 14; ++t) {
    WAITV(4);                       // tile t's 4 loads done; t+1's in flight
    BAR();
    STAGE((t + 2) % 3, t + 2);      // overwrites buf consumed at iter t-1
    COMPUTE(t % 3);
  }
  WAITV(4); BAR(); COMPUTE(2);      // t=14 (tile 15's loads still in flight)
  WAITV(0); BAR(); COMPUTE(0);      // t=15
#undef STAGE
#undef COMPUTE
#undef WAITV
#undef BAR

  // ---- epilogue: a = sigmoid(-gate), v = sigmoid(gate)*g(hidden); av packed;
  // ---- fused scan pass1: per 32-row chunk, (A,B) = chunk-composed affine map.
  const int row_w = m_base + 128 * wr;
#pragma unroll
  for (int h = 0; h < 4; ++h) {          // chunk: rows [32h, 32h+32) of wave
    float Ar[2][2], Br[2][2];            // [n][mm]
#pragma unroll
    for (int mm = 0; mm < 2; ++mm) {
      const int m = 2 * h + mm;
#pragma unroll
      for (int n = 0; n < 2; ++n) {
        float A = 1.f, Bv = 0.f;
        const int dch = d0 + 32 * wc + 16 * n + l15;
#pragma unroll
        for (int r = 0; r < 4; ++r) {
          float hid = acc[m][n][r];
          float gt  = acc[m][n + 2][r];
          float e   = __expf(gt);
          float inv = 1.f / (1.f + e);         // a = sigmoid(-gate)
          float g   = (hid >= 0.f) ? (hid + 0.5f) : (1.f / (1.f + __expf(-hid)));
          float v   = (e * inv) * g;           // z * g
          u16 abf = f2bf(inv);
          u16 vbf = f2bf(v);
          const int grow = row_w + 16 * m + 4 * lh + r;
          av_buf[(size_t)grow * D_DIM + dch] = (u32)abf | ((u32)vbf << 16);
          float afv = bf2f(abf), vfv = bf2f(vbf);
          Bv = afv * Bv + vfv;
          A *= afv;
        }
        Ar[n][mm] = A; Br[n][mm] = Bv;
      }
    }
    // inclusive scan across lh (4 segments of 4 rows each), per (n, mm)
#pragma unroll
    for (int n = 0; n < 2; ++n)
#pragma unroll
      for (int mm = 0; mm < 2; ++mm) {
        float A = Ar[n][mm], Bv = Br[n][mm];
#pragma unroll
        for (int d = 1; d <= 2; d <<= 1) {
          float pA = __shfl(A, lane - 16 * d);
          float pB = __shfl(Bv, lane - 16 * d);
          if (lh >= d) { Bv = A * pB + Bv; A = A * pA; }
        }
        Ar[n][mm] = A; Br[n][mm] = Bv;
      }
    if (lh == 3) {   // lanes 48..63 hold full 16-row segment results
      const int grow = row_w + 32 * h;
      const int b = grow >> 13;           // / 8192
      const int c = (grow & 8191) >> 5;   // / 32
      const size_t o = ((size_t)(b * NC + c)) * D_DIM;
#pragma unroll
      for (int n = 0; n < 2; ++n) {
        const int dch = d0 + 32 * wc + 16 * n + l15;
        float Ac = Ar[n][0] * Ar[n][1];
        float Bc = Ar[n][1] * Br[n][0] + Br[n][1];
        Asum[o + dch] = Ac;
        Bsum[o + dch] = Bc;
      }
    }
  }
}

// ------- chunk-level scan: one wave per (b,d) channel, shfl affine scan -------
// Lane l owns chunks 4l..4l+3: compose 4, wave inclusive-scan (shfl_up, 6
// steps), shift to exclusive -> carry-in per chunk (h0 = 0 -> carry = Eb).

__global__ __launch_bounds__(256) void scan_pass2(const float* __restrict__ Asum,
                                                  const float* __restrict__ Bsum,
                                                  float* __restrict__ carry) {
  const int w    = (blockIdx.x << 2) + (threadIdx.x >> 6);  // 0..2047
  const int lane = threadIdx.x & 63;
  const int b = w >> 9;
  const int d = w & 511;
  const size_t base = ((size_t)(b * NC + lane * 4)) * D_DIM + d;
  float A[4], Bv[4];
#pragma unroll
  for (int i = 0; i < 4; ++i) {
    A[i]  = Asum[base + (size_t)i * D_DIM];
    Bv[i] = Bsum[base + (size_t)i * D_DIM];
  }
  // lane-local composite (apply chunk 4l first)
  float La = 1.f, Lb = 0.f;
#pragma unroll
  for (int i = 0; i < 4; ++i) { Lb = A[i] * Lb + Bv[i]; La *= A[i]; }
  // inclusive scan across lanes: compose(prev, cur) = (pa*ca, ca*pb + cb)
  float Sa = La, Sb = Lb;
#pragma unroll
  for (int dlt = 1; dlt < 64; dlt <<= 1) {
    float pa = __shfl_up(Sa, dlt, 64);
    float pb = __shfl_up(Sb, dlt, 64);
    if (lane >= dlt) { Sb = Sa * pb + Sb; Sa = Sa * pa; }
  }
  // exclusive prefix (identity at lane 0); h0 = 0 -> carry-in = Eb
  float Eb = __shfl_up(Sb, 1, 64);
  float h = (lane == 0) ? 0.f : Eb;
#pragma unroll
  for (int i = 0; i < 4; ++i) {
    carry[base + (size_t)i * D_DIM] = h;
    h = A[i] * h + Bv[i];
  }
}

// ---------------- final within-chunk scan + output ----------------

__global__ __launch_bounds__(128) void scan_pass3(const u32* __restrict__ av_buf,
                                                  const float4* __restrict__ carry,
                                                  float4* __restrict__ out) {
  const int c = blockIdx.x;
  const int b = blockIdx.y;
  const int d4 = threadIdx.x;
  float4 hh = carry[((size_t)(b * NC + c)) * 128 + d4];
  float h[4] = {hh.x, hh.y, hh.z, hh.w};
  size_t base = ((size_t)b * T_DIM + (size_t)c * LCH) * D_DIM + d4 * 4;
  for (int t = 0; t < LCH; ++t) {
    uint4 w = *reinterpret_cast<const uint4*>(av_buf + base);
    h[0] = bf2f(w.x & 0xffff) * h[0] + bf2f(w.x >> 16);
    h[1] = bf2f(w.y & 0xffff) * h[1] + bf2f(w.y >> 16);
    h[2] = bf2f(w.z & 0xffff) * h[2] + bf2f(w.z >> 16);
    h[3] = bf2f(w.w & 0xffff) * h[3] + bf2f(w.w >> 16);
    out[base >> 2] = make_float4(h[0], h[1], h[2], h[3]);
    base += D_DIM;
  }
}

// ---------------- launch ----------------

extern "C" void kernel_launch(void* const* d_in, const int* in_sizes, int n_in,
                              void* d_out, int out_size, void* d_ws, size_t ws_size,
                              hipStream_t stream) {
  const float* x = (const float*)d_in[0];   // [4,8192,512]
  const float* W = (const float*)d_in[1];   // [512,1024]
  float* out = (float*)d_out;               // [4,8192,512]

  char* ws = (char*)d_ws;
  u16*   xb     = (u16*)(ws + 0);             // 33,554,432
  u16*   wtp    = (u16*)(ws + 33554432);      //  1,048,576
  u32*   av_buf = (u32*)(ws + 34603008);      // 67,108,864 (a lo16 | v hi16)
  float* Asum   = (float*)(ws + 101711872);   //  2,097,152
  float* Bsum   = (float*)(ws + 103809024);   //  2,097,152
  float* carry  = (float*)(ws + 105906176);   //  2,097,152  (end 108,003,328)
  if (ws_size < 108003328ULL) return;

  convert_x<<<2048, 256, 0, stream>>>((const float4*)x, xb, (M_DIM * K_DIM) / 4);
  convert_wt<<<256, 256, 0, stream>>>(W, wtp);
  gemm_act<<<dim3(M_DIM / 256, D_DIM / 128), 512, 0, stream>>>(xb, wtp, av_buf, Asum, Bsum);
  scan_pass2<<<512, 256, 0, stream>>>(Asum, Bsum, carry);
  scan_pass3<<<dim3(NC, B_DIM), 128, 0, stream>>>(av_buf, (const float4*)carry, (float4*)out);
}

// Round 13
// 115.232 us; speedup vs baseline: 1.0004x; 1.0004x over previous
//
#include <hip/hip_runtime.h>

typedef unsigned short u16;
typedef unsigned int   u32;

typedef __bf16 bf16x8 __attribute__((ext_vector_type(8)));
typedef float  f32x4  __attribute__((ext_vector_type(4)));

#define B_DIM 4
#define T_DIM 8192
#define D_DIM 512
#define M_DIM (B_DIM * T_DIM)   // 32768
#define K_DIM D_DIM             // 512
#define NC    256               // chunks along T
#define LCH   32                // chunk length (NC*LCH == T_DIM)

__device__ __forceinline__ u16 f2bf(float f) {
  u32 u = __float_as_uint(f);
  u32 r = (u + 0x7FFFu + ((u >> 16) & 1u)) >> 16;   // RNE
  return (u16)r;
}
__device__ __forceinline__ float bf2f(u16 b) {
  return __uint_as_float(((u32)b) << 16);
}

// async global->LDS, 16B per lane; lds dest is wave-uniform base + lane*16
__device__ __forceinline__ void gload_lds16(const u16* g, u16* lds) {
  __builtin_amdgcn_global_load_lds(
      (const __attribute__((address_space(1))) void*)g,
      (__attribute__((address_space(3))) void*)lds, 16, 0, 0);
}

// ---------------- conversion kernels ----------------

__global__ void convert_x(const float4* __restrict__ in, u16* __restrict__ out, int n4) {
  int i = blockIdx.x * blockDim.x + threadIdx.x;
  int stride = gridDim.x * blockDim.x;
  for (; i < n4; i += stride) {
    float4 f = in[i];
    u32 w0 = (u32)f2bf(f.x) | ((u32)f2bf(f.y) << 16);
    u32 w1 = (u32)f2bf(f.z) | ((u32)f2bf(f.w) << 16);
    *reinterpret_cast<uint2*>(out + (size_t)i * 4) = make_uint2(w0, w1);
  }
}

// W [K=512][N=1024] fp32 -> wt [N=1024][K=512] bf16 (transposed)
__global__ void convert_wt(const float* __restrict__ W, u16* __restrict__ wt) {
  int idx = blockIdx.x * blockDim.x + threadIdx.x;  // 65536 threads
  int n  = idx & 1023;
  int k0 = (idx >> 10) * 8;
  float f[8];
#pragma unroll
  for (int j = 0; j < 8; ++j) f[j] = W[(size_t)(k0 + j) * 1024 + n];
  u32 w[4];
#pragma unroll
  for (int j = 0; j < 4; ++j)
    w[j] = (u32)f2bf(f[2 * j]) | ((u32)f2bf(f[2 * j + 1]) << 16);
  *reinterpret_cast<uint4*>(wt + (size_t)n * 512 + k0) = make_uint4(w[0], w[1], w[2], w[3]);
}

// ---- GEMM: 256Mx128N, 4 waves, wave 128x64 (acc[8][4]), BK=32, 3-buf -------
// Round-9 rolling counted-vmcnt schedule (proven), re-parametrized for 256
// threads: 6 gload_lds per STAGE (A 4 calls + B 2 calls, 4KB each), WAITV(6).
// Per-wave tile 128x64 cuts LDS reads/MFMA 0.5 -> 0.375; LDS 72KB -> 2
// blocks/CU retained.  Iter t: s_waitcnt vmcnt(6) [tile t's 6 loads done;
// t+1's in flight] -> s_barrier -> STAGE(t+2) -> COMPUTE(t).  Never vmcnt(0)
// until the tail (T4).  Stage t+2 overwrites buf consumed at iter t-1.
// Swizzle: slot_phys = slot_log^(pair&7), staged via inverse-swizzled GLOBAL
// source (rule #21; proven 0 conflicts).
// B tile rows j (call i: j = 64i + lrow), p=j>>5: gn = (p&1)*512 + d0 +
// (p>>1)*32 + (j&31) -> wave wc in {0,1}: hidden=acc[m][n], gate=acc[m][n+2]
// (n<2), channel dch = d0 + 32*wc + 16n + l15, d0 = blockIdx.y*64.

#define BK 32
#define NT 16

__global__ __launch_bounds__(256, 2) void gemm_act(const u16* __restrict__ xb,
                                                   const u16* __restrict__ wt,
                                                   u32* __restrict__ av_buf,
                                                   float* __restrict__ Asum,
                                                   float* __restrict__ Bsum) {
  __shared__ u16 As[3][8192];   // 3 x 16 KB (256 rows x 32 k)
  __shared__ u16 Bs[3][4096];   // 3 x 8 KB  (128 rows x 32 k)

  const int tid  = threadIdx.x;
  const int lane = tid & 63;
  const int wave = tid >> 6;        // 0..3
  const int l15  = lane & 15;
  const int lh   = lane >> 4;       // 0..3
  const int wr   = wave >> 1;       // 0..1  (row half: 128 rows)
  const int wc   = wave & 1;        // 0..1  (col half: 64 cols)
  const int m_base = blockIdx.x * 256;
  const int d0     = blockIdx.y * 64;

  // staging: 256 threads -> 4KB per call (32 pairs); logical source:
  const int pairl = tid >> 3;                   // 0..31
  const int slog  = (tid & 7) ^ (pairl & 7);    // logical slot
  const int lrow  = (pairl << 1) | (slog >> 2); // 0..63
  const int scol  = (slog & 3) << 3;            // k elem offset 0/8/16/24
  int garow[4];
#pragma unroll
  for (int i = 0; i < 4; ++i) garow[i] = m_base + 64 * i + lrow;   // A call i
  const int p0  = lrow >> 5;                    // B call 0: j = lrow
  const int gn0 = (p0 ? 512 : 0) + d0 + (lrow & 31);
  const int gn1 = gn0 + 32;                     // B call 1: j = 64 + lrow
  const int ldsw = wave * 512;                  // wave's 1KB within a call

  f32x4 acc[8][4];
#pragma unroll
  for (int m = 0; m < 8; ++m)
#pragma unroll
    for (int n = 0; n < 4; ++n)
      acc[m][n] = (f32x4){0.f, 0.f, 0.f, 0.f};

#define STAGE(buf, kt)                                                      \
  do {                                                                      \
    const int ko = (kt) * BK + scol;                                        \
    gload_lds16(xb + (size_t)garow[0] * K_DIM + ko, &As[buf][ldsw]);        \
    gload_lds16(xb + (size_t)garow[1] * K_DIM + ko, &As[buf][2048 + ldsw]); \
    gload_lds16(xb + (size_t)garow[2] * K_DIM + ko, &As[buf][4096 + ldsw]); \
    gload_lds16(xb + (size_t)garow[3] * K_DIM + ko, &As[buf][6144 + ldsw]); \
    gload_lds16(wt + (size_t)gn0 * K_DIM + ko, &Bs[buf][ldsw]);             \
    gload_lds16(wt + (size_t)gn1 * K_DIM + ko, &Bs[buf][2048 + ldsw]);      \
  } while (0)

  // swizzled read offset (elems) for logical (row, k-chunk lh)
#define AOFF(row) (((row) >> 1) * 64 + (((((((row) & 1) << 2) | lh)) ^ (((row) >> 1) & 7)) << 3))

#define COMPUTE(cur)                                                        \
  do {                                                                      \
    bf16x8 bfr[4];                                                          \
    _Pragma("unroll")                                                       \
    for (int n = 0; n < 4; ++n)                                             \
      bfr[n] = *reinterpret_cast<const bf16x8*>(&Bs[cur][AOFF(64 * wc + 16 * n + l15)]); \
    _Pragma("unroll")                                                       \
    for (int mh = 0; mh < 2; ++mh) {                                        \
      bf16x8 af[4];                                                         \
      _Pragma("unroll")                                                     \
      for (int mm = 0; mm < 4; ++mm)                                        \
        af[mm] = *reinterpret_cast<const bf16x8*>(&As[cur][AOFF(128 * wr + 64 * mh + 16 * mm + l15)]); \
      _Pragma("unroll")                                                     \
      for (int mm = 0; mm < 4; ++mm)                                        \
        _Pragma("unroll")                                                   \
        for (int n = 0; n < 4; ++n)                                         \
          acc[4 * mh + mm][n] = __builtin_amdgcn_mfma_f32_16x16x32_bf16(af[mm], bfr[n], acc[4 * mh + mm][n], 0, 0, 0); \
    }                                                                       \
  } while (0)

#define WAITV(N) asm volatile("s_waitcnt vmcnt(" #N ")" ::: "memory")
#define BAR()    asm volatile("s_barrier" ::: "memory")

  STAGE(0, 0);
  STAGE(1, 1);
#pragma unroll
  for (int t = 0; t < 14; ++t) {
    WAITV(6);                       // tile t's 6 loads done; t+1's in flight
    BAR();
    STAGE((t + 2) % 3, t + 2);      // overwrites buf consumed at iter t-1
    COMPUTE(t % 3);
  }
  WAITV(6); BAR(); COMPUTE(2);      // t=14 (tile 15's loads still in flight)
  WAITV(0); BAR(); COMPUTE(0);      // t=15
#undef STAGE
#undef COMPUTE
#undef WAITV
#undef BAR

  // ---- epilogue: a = sigmoid(-gate), v = sigmoid(gate)*g(hidden); av packed;
  // ---- fused scan pass1: per 32-row chunk, (A,B) = chunk-composed affine map.
  const int row_w = m_base + 128 * wr;
#pragma unroll
  for (int h = 0; h < 4; ++h) {          // chunk: rows [32h, 32h+32) of wave
    float Ar[2][2], Br[2][2];            // [n][mm]
#pragma unroll
    for (int mm = 0; mm < 2; ++mm) {
      const int m = 2 * h + mm;
#pragma unroll
      for (int n = 0; n < 2; ++n) {
        float A = 1.f, Bv = 0.f;
        const int dch = d0 + 32 * wc + 16 * n + l15;
#pragma unroll
        for (int r = 0; r < 4; ++r) {
          float hid = acc[m][n][r];
          float gt  = acc[m][n + 2][r];
          float e   = __expf(gt);
          float inv = 1.f / (1.f + e);         // a = sigmoid(-gate)
          float g   = (hid >= 0.f) ? (hid + 0.5f) : (1.f / (1.f + __expf(-hid)));
          float v   = (e * inv) * g;           // z * g
          u16 abf = f2bf(inv);
          u16 vbf = f2bf(v);
          const int grow = row_w + 16 * m + 4 * lh + r;
          av_buf[(size_t)grow * D_DIM + dch] = (u32)abf | ((u32)vbf << 16);
          float afv = bf2f(abf), vfv = bf2f(vbf);
          Bv = afv * Bv + vfv;
          A *= afv;
        }
        Ar[n][mm] = A; Br[n][mm] = Bv;
      }
    }
    // inclusive scan across lh (4 segments of 4 rows each), per (n, mm)
#pragma unroll
    for (int n = 0; n < 2; ++n)
#pragma unroll
      for (int mm = 0; mm < 2; ++mm) {
        float A = Ar[n][mm], Bv = Br[n][mm];
#pragma unroll
        for (int d = 1; d <= 2; d <<= 1) {
          float pA = __shfl(A, lane - 16 * d);
          float pB = __shfl(Bv, lane - 16 * d);
          if (lh >= d) { Bv = A * pB + Bv; A = A * pA; }
        }
        Ar[n][mm] = A; Br[n][mm] = Bv;
      }
    if (lh == 3) {   // lanes 48..63 hold full 16-row segment results
      const int grow = row_w + 32 * h;
      const int b = grow >> 13;           // / 8192
      const int c = (grow & 8191) >> 5;   // / 32
      const size_t o = ((size_t)(b * NC + c)) * D_DIM;
#pragma unroll
      for (int n = 0; n < 2; ++n) {
        const int dch = d0 + 32 * wc + 16 * n + l15;
        float Ac = Ar[n][0] * Ar[n][1];
        float Bc = Ar[n][1] * Br[n][0] + Br[n][1];
        Asum[o + dch] = Ac;
        Bsum[o + dch] = Bc;
      }
    }
  }
}

// ------- chunk-level scan: one wave per (b,d) channel, shfl affine scan -------
// Lane l owns chunks 4l..4l+3: compose 4, wave inclusive-scan (shfl_up, 6
// steps), shift to exclusive -> carry-in per chunk (h0 = 0 -> carry = Eb).

__global__ __launch_bounds__(256) void scan_pass2(const float* __restrict__ Asum,
                                                  const float* __restrict__ Bsum,
                                                  float* __restrict__ carry) {
  const int w    = (blockIdx.x << 2) + (threadIdx.x >> 6);  // 0..2047
  const int lane = threadIdx.x & 63;
  const int b = w >> 9;
  const int d = w & 511;
  const size_t base = ((size_t)(b * NC + lane * 4)) * D_DIM + d;
  float A[4], Bv[4];
#pragma unroll
  for (int i = 0; i < 4; ++i) {
    A[i]  = Asum[base + (size_t)i * D_DIM];
    Bv[i] = Bsum[base + (size_t)i * D_DIM];
  }
  // lane-local composite (apply chunk 4l first)
  float La = 1.f, Lb = 0.f;
#pragma unroll
  for (int i = 0; i < 4; ++i) { Lb = A[i] * Lb + Bv[i]; La *= A[i]; }
  // inclusive scan across lanes: compose(prev, cur) = (pa*ca, ca*pb + cb)
  float Sa = La, Sb = Lb;
#pragma unroll
  for (int dlt = 1; dlt < 64; dlt <<= 1) {
    float pa = __shfl_up(Sa, dlt, 64);
    float pb = __shfl_up(Sb, dlt, 64);
    if (lane >= dlt) { Sb = Sa * pb + Sb; Sa = Sa * pa; }
  }
  // exclusive prefix (identity at lane 0); h0 = 0 -> carry-in = Eb
  float Eb = __shfl_up(Sb, 1, 64);
  float h = (lane == 0) ? 0.f : Eb;
#pragma unroll
  for (int i = 0; i < 4; ++i) {
    carry[base + (size_t)i * D_DIM] = h;
    h = A[i] * h + Bv[i];
  }
}

// ---------------- final within-chunk scan + output ----------------

__global__ __launch_bounds__(128) void scan_pass3(const u32* __restrict__ av_buf,
                                                  const float4* __restrict__ carry,
                                                  float4* __restrict__ out) {
  const int c = blockIdx.x;
  const int b = blockIdx.y;
  const int d4 = threadIdx.x;
  float4 hh = carry[((size_t)(b * NC + c)) * 128 + d4];
  float h[4] = {hh.x, hh.y, hh.z, hh.w};
  size_t base = ((size_t)b * T_DIM + (size_t)c * LCH) * D_DIM + d4 * 4;
  for (int t = 0; t < LCH; ++t) {
    uint4 w = *reinterpret_cast<const uint4*>(av_buf + base);
    h[0] = bf2f(w.x & 0xffff) * h[0] + bf2f(w.x >> 16);
    h[1] = bf2f(w.y & 0xffff) * h[1] + bf2f(w.y >> 16);
    h[2] = bf2f(w.z & 0xffff) * h[2] + bf2f(w.z >> 16);
    h[3] = bf2f(w.w & 0xffff) * h[3] + bf2f(w.w >> 16);
    out[base >> 2] = make_float4(h[0], h[1], h[2], h[3]);
    base += D_DIM;
  }
}

// ---------------- launch ----------------

extern "C" void kernel_launch(void* const* d_in, const int* in_sizes, int n_in,
                              void* d_out, int out_size, void* d_ws, size_t ws_size,
                              hipStream_t stream) {
  const float* x = (const float*)d_in[0];   // [4,8192,512]
  const float* W = (const float*)d_in[1];   // [512,1024]
  float* out = (float*)d_out;               // [4,8192,512]

  char* ws = (char*)d_ws;
  u16*   xb     = (u16*)(ws + 0);             // 33,554,432
  u16*   wtp    = (u16*)(ws + 33554432);      //  1,048,576
  u32*   av_buf = (u32*)(ws + 34603008);      // 67,108,864 (a lo16 | v hi16)
  float* Asum   = (float*)(ws + 101711872);   //  2,097,152
  float* Bsum   = (float*)(ws + 103809024);   //  2,097,152
  float* carry  = (float*)(ws + 105906176);   //  2,097,152  (end 108,003,328)
  if (ws_size < 108003328ULL) return;

  convert_x<<<2048, 256, 0, stream>>>((const float4*)x, xb, (M_DIM * K_DIM) / 4);
  convert_wt<<<256, 256, 0, stream>>>(W, wtp);
  gemm_act<<<dim3(M_DIM / 256, D_DIM / 64), 256, 0, stream>>>(xb, wtp, av_buf, Asum, Bsum);
  scan_pass2<<<512, 256, 0, stream>>>(Asum, Bsum, carry);
  scan_pass3<<<dim3(NC, B_DIM), 128, 0, stream>>>(av_buf, (const float4*)carry, (float4*)out);
}

// Round 14
// 109.471 us; speedup vs baseline: 1.0531x; 1.0526x over previous
//
#include <hip/hip_runtime.h>

typedef unsigned short u16;
typedef unsigned int   u32;

typedef __bf16 bf16x8 __attribute__((ext_vector_type(8)));
typedef float  f32x4  __attribute__((ext_vector_type(4)));

#define B_DIM 4
#define T_DIM 8192
#define D_DIM 512
#define M_DIM (B_DIM * T_DIM)   // 32768
#define K_DIM D_DIM             // 512
#define NC    256               // chunks along T
#define LCH   32                // chunk length (NC*LCH == T_DIM)

__device__ __forceinline__ u16 f2bf(float f) {
  u32 u = __float_as_uint(f);
  u32 r = (u + 0x7FFFu + ((u >> 16) & 1u)) >> 16;   // RNE
  return (u16)r;
}
__device__ __forceinline__ float bf2f(u16 b) {
  return __uint_as_float(((u32)b) << 16);
}

// async global->LDS, 16B per lane; lds dest is wave-uniform base + lane*16
__device__ __forceinline__ void gload_lds16(const u16* g, u16* lds) {
  __builtin_amdgcn_global_load_lds(
      (const __attribute__((address_space(1))) void*)g,
      (__attribute__((address_space(3))) void*)lds, 16, 0, 0);
}

// ---------------- conversion kernels ----------------

__global__ void convert_x(const float4* __restrict__ in, u16* __restrict__ out, int n4) {
  int i = blockIdx.x * blockDim.x + threadIdx.x;
  int stride = gridDim.x * blockDim.x;
  for (; i < n4; i += stride) {
    float4 f = in[i];
    u32 w0 = (u32)f2bf(f.x) | ((u32)f2bf(f.y) << 16);
    u32 w1 = (u32)f2bf(f.z) | ((u32)f2bf(f.w) << 16);
    *reinterpret_cast<uint2*>(out + (size_t)i * 4) = make_uint2(w0, w1);
  }
}

// W [K=512][N=1024] fp32 -> wt [N=1024][K=512] bf16 (transposed)
__global__ void convert_wt(const float* __restrict__ W, u16* __restrict__ wt) {
  int idx = blockIdx.x * blockDim.x + threadIdx.x;  // 65536 threads
  int n  = idx & 1023;
  int k0 = (idx >> 10) * 8;
  float f[8];
#pragma unroll
  for (int j = 0; j < 8; ++j) f[j] = W[(size_t)(k0 + j) * 1024 + n];
  u32 w[4];
#pragma unroll
  for (int j = 0; j < 4; ++j)
    w[j] = (u32)f2bf(f[2 * j]) | ((u32)f2bf(f[2 * j + 1]) << 16);
  *reinterpret_cast<uint4*>(wt + (size_t)n * 512 + k0) = make_uint4(w[0], w[1], w[2], w[3]);
}

// ---- GEMM: 256Mx128N, 8 waves (wr 0..3, wc 0..1), wave 64x64, BK=32 --------
// r9 3-buf rolling counted-vmcnt schedule (proven 56.4us) + 2-PHASE SPLIT:
// each tile's 16 MFMA split at m-half with a mid-barrier; stage calls split
// A(2)/B(1) across the phases; setprio(1) around each 8-MFMA cluster.
// Mechanism (T3->T5): phases create {ds_read vs MFMA} wave role diversity on
// the CU; setprio favors MFMA-entering waves -> LDS bursts and MFMA bursts
// overlap across waves instead of lockstep alternation.
// Iter t: s_waitcnt vmcnt(3) [tile t's 3 loads done; t+1's in flight] ->
// s_barrier -> ph0{STAGE_A(t+2), bfr+af01 reads, 8 MFMA} -> s_barrier ->
// ph1{STAGE_B(t+2), af23 reads, 8 MFMA}.  Never vmcnt(0) until the tail.
// LDS per buf: A 256x32 (16KB), B 128x32 (8KB); 3 bufs = 72KB, 2 blocks/CU.
// Swizzle: slot_phys = slot_log^(pair&7) via inverse-swizzled GLOBAL source
// (rule #21; proven 0 conflicts).
// B tile rows p=row>>5: gn = (p&1)*512 + d0 + (p>>1)*32 + (row&31) ->
// hidden=acc[m][n], gate=acc[m][n+2] (n<2), ch dch = d0+32*wc+16n+l15.

#define BK 32
#define NT 16

__global__ __launch_bounds__(512, 4) void gemm_act(const u16* __restrict__ xb,
                                                   const u16* __restrict__ wt,
                                                   u32* __restrict__ av_buf,
                                                   float* __restrict__ Asum,
                                                   float* __restrict__ Bsum) {
  __shared__ u16 As[3][8192];   // 3 x 16 KB (256 rows x 32 k)
  __shared__ u16 Bs[3][4096];   // 3 x 8 KB  (128 rows x 32 k)

  const int tid  = threadIdx.x;
  const int lane = tid & 63;
  const int wave = tid >> 6;        // 0..7
  const int l15  = lane & 15;
  const int lh   = lane >> 4;       // 0..3
  const int wr   = wave >> 1;       // 0..3
  const int wc   = wave & 1;        // 0..1
  const int m_base = blockIdx.x * 256;
  const int d0     = blockIdx.y * 64;

  // staging: slot s = tid (0..511); pair = s>>3, phys = s&7; logical source:
  const int pairl = tid >> 3;                  // 0..63 (pair within region)
  const int slog  = (tid & 7) ^ (pairl & 7);   // logical slot
  const int lrow  = (pairl << 1) | (slog >> 2); // 0..127
  const int scol  = (slog & 3) << 3;            // k elem offset 0/8/16/24
  const int garow0 = m_base + lrow;             // A call 0: rows 0..127
  const int garow1 = garow0 + 128;              // A call 1: rows 128..255
  const int pB = lrow >> 5;
  const int gn = ((pB & 1) ? 512 : 0) + d0 + ((pB >> 1) << 5) + (lrow & 31);
  const int ldsw = wave * 512;                  // wave's 1KB within a call

  f32x4 acc[4][4];
#pragma unroll
  for (int m = 0; m < 4; ++m)
#pragma unroll
    for (int n = 0; n < 4; ++n)
      acc[m][n] = (f32x4){0.f, 0.f, 0.f, 0.f};

#define STAGE_A(buf, kt)                                                    \
  do {                                                                      \
    const int ko = (kt) * BK + scol;                                        \
    gload_lds16(xb + (size_t)garow0 * K_DIM + ko, &As[buf][ldsw]);          \
    gload_lds16(xb + (size_t)garow1 * K_DIM + ko, &As[buf][4096 + ldsw]);   \
  } while (0)
#define STAGE_B(buf, kt)                                                    \
  gload_lds16(wt + (size_t)gn * K_DIM + (kt) * BK + scol, &Bs[buf][ldsw])

  // swizzled read offset (elems) for logical (row, k-chunk lh)
#define AOFF(row) (((row) >> 1) * 64 + (((((((row) & 1) << 2) | lh)) ^ (((row) >> 1) & 7)) << 3))

#define WAITV(N) asm volatile("s_waitcnt vmcnt(" #N ")" ::: "memory")
#define BAR()    asm volatile("s_barrier" ::: "memory")

  // tile body with 2-phase split; stage_kt = t+2 (or skipped at tail)
#define TILE(cur, do_stage, skt)                                            \
  do {                                                                      \
    bf16x8 af[4], bfr[4];                                                   \
    if (do_stage) STAGE_A((skt) % 3, skt);                                  \
    _Pragma("unroll")                                                       \
    for (int n = 0; n < 4; ++n)                                             \
      bfr[n] = *reinterpret_cast<const bf16x8*>(&Bs[cur][AOFF(64 * wc + 16 * n + l15)]); \
    _Pragma("unroll")                                                       \
    for (int m = 0; m < 2; ++m)                                             \
      af[m] = *reinterpret_cast<const bf16x8*>(&As[cur][AOFF(64 * wr + 16 * m + l15)]); \
    __builtin_amdgcn_s_setprio(1);                                          \
    _Pragma("unroll")                                                       \
    for (int m = 0; m < 2; ++m)                                             \
      _Pragma("unroll")                                                     \
      for (int n = 0; n < 4; ++n)                                           \
        acc[m][n] = __builtin_amdgcn_mfma_f32_16x16x32_bf16(af[m], bfr[n], acc[m][n], 0, 0, 0); \
    __builtin_amdgcn_s_setprio(0);                                          \
    BAR();                                     /* phase boundary */         \
    if (do_stage) STAGE_B((skt) % 3, skt);                                  \
    _Pragma("unroll")                                                       \
    for (int m = 2; m < 4; ++m)                                             \
      af[m] = *reinterpret_cast<const bf16x8*>(&As[cur][AOFF(64 * wr + 16 * m + l15)]); \
    __builtin_amdgcn_s_setprio(1);                                          \
    _Pragma("unroll")                                                       \
    for (int m = 2; m < 4; ++m)                                             \
      _Pragma("unroll")                                                     \
      for (int n = 0; n < 4; ++n)                                           \
        acc[m][n] = __builtin_amdgcn_mfma_f32_16x16x32_bf16(af[m], bfr[n], acc[m][n], 0, 0, 0); \
    __builtin_amdgcn_s_setprio(0);                                          \
  } while (0)

  STAGE_A(0, 0); STAGE_B(0, 0);
  STAGE_A(1, 1); STAGE_B(1, 1);
#pragma unroll
  for (int t = 0; t < 14; ++t) {
    WAITV(3);                       // tile t's 3 loads done; t+1's in flight
    BAR();
    TILE(t % 3, true, t + 2);       // stages tile t+2 into buf consumed at t-1
  }
  WAITV(3); BAR(); TILE(14 % 3, false, 0);   // t=14 (tile 15 in flight)
  WAITV(0); BAR(); TILE(15 % 3, false, 0);   // t=15
#undef TILE
#undef STAGE_A
#undef STAGE_B
#undef WAITV
#undef BAR

  // ---- epilogue: a = sigmoid(-gate), v = sigmoid(gate)*g(hidden); av packed;
  // ---- fused scan pass1: per 32-row chunk, (A,B) = chunk-composed affine map.
  const int row_w = m_base + 64 * wr;
#pragma unroll
  for (int h = 0; h < 2; ++h) {          // chunk half: rows [32h, 32h+32) of wave
    float Ar[2][2], Br[2][2];            // [n][mm]
#pragma unroll
    for (int mm = 0; mm < 2; ++mm) {
      const int m = 2 * h + mm;
#pragma unroll
      for (int n = 0; n < 2; ++n) {
        float A = 1.f, Bv = 0.f;
        const int dch = d0 + 32 * wc + 16 * n + l15;
#pragma unroll
        for (int r = 0; r < 4; ++r) {
          float hid = acc[m][n][r];
          float gt  = acc[m][n + 2][r];
          float e   = __expf(gt);
          float inv = 1.f / (1.f + e);         // a = sigmoid(-gate)
          float g   = (hid >= 0.f) ? (hid + 0.5f) : (1.f / (1.f + __expf(-hid)));
          float v   = (e * inv) * g;           // z * g
          u16 abf = f2bf(inv);
          u16 vbf = f2bf(v);
          const int grow = row_w + 16 * m + 4 * lh + r;
          av_buf[(size_t)grow * D_DIM + dch] = (u32)abf | ((u32)vbf << 16);
          float afv = bf2f(abf), vfv = bf2f(vbf);
          Bv = afv * Bv + vfv;
          A *= afv;
        }
        Ar[n][mm] = A; Br[n][mm] = Bv;
      }
    }
    // inclusive scan across lh (4 segments of 4 rows each), per (n, mm)
#pragma unroll
    for (int n = 0; n < 2; ++n)
#pragma unroll
      for (int mm = 0; mm < 2; ++mm) {
        float A = Ar[n][mm], Bv = Br[n][mm];
#pragma unroll
        for (int d = 1; d <= 2; d <<= 1) {
          float pA = __shfl(A, lane - 16 * d);
          float pB = __shfl(Bv, lane - 16 * d);
          if (lh >= d) { Bv = A * pB + Bv; A = A * pA; }
        }
        Ar[n][mm] = A; Br[n][mm] = Bv;
      }
    if (lh == 3) {   // lanes 48..63 hold full 16-row segment results
      const int grow = row_w + 32 * h;
      const int b = grow >> 13;           // / 8192
      const int c = (grow & 8191) >> 5;   // / 32
      const size_t o = ((size_t)(b * NC + c)) * D_DIM;
#pragma unroll
      for (int n = 0; n < 2; ++n) {
        const int dch = d0 + 32 * wc + 16 * n + l15;
        float Ac = Ar[n][0] * Ar[n][1];
        float Bc = Ar[n][1] * Br[n][0] + Br[n][1];
        Asum[o + dch] = Ac;
        Bsum[o + dch] = Bc;
      }
    }
  }
}

// ------- chunk-level scan: one wave per (b,d) channel, shfl affine scan -------
// Lane l owns chunks 4l..4l+3: compose 4, wave inclusive-scan (shfl_up, 6
// steps), shift to exclusive -> carry-in per chunk (h0 = 0 -> carry = Eb).

__global__ __launch_bounds__(256) void scan_pass2(const float* __restrict__ Asum,
                                                  const float* __restrict__ Bsum,
                                                  float* __restrict__ carry) {
  const int w    = (blockIdx.x << 2) + (threadIdx.x >> 6);  // 0..2047
  const int lane = threadIdx.x & 63;
  const int b = w >> 9;
  const int d = w & 511;
  const size_t base = ((size_t)(b * NC + lane * 4)) * D_DIM + d;
  float A[4], Bv[4];
#pragma unroll
  for (int i = 0; i < 4; ++i) {
    A[i]  = Asum[base + (size_t)i * D_DIM];
    Bv[i] = Bsum[base + (size_t)i * D_DIM];
  }
  // lane-local composite (apply chunk 4l first)
  float La = 1.f, Lb = 0.f;
#pragma unroll
  for (int i = 0; i < 4; ++i) { Lb = A[i] * Lb + Bv[i]; La *= A[i]; }
  // inclusive scan across lanes: compose(prev, cur) = (pa*ca, ca*pb + cb)
  float Sa = La, Sb = Lb;
#pragma unroll
  for (int dlt = 1; dlt < 64; dlt <<= 1) {
    float pa = __shfl_up(Sa, dlt, 64);
    float pb = __shfl_up(Sb, dlt, 64);
    if (lane >= dlt) { Sb = Sa * pb + Sb; Sa = Sa * pa; }
  }
  // exclusive prefix (identity at lane 0); h0 = 0 -> carry-in = Eb
  float Eb = __shfl_up(Sb, 1, 64);
  float h = (lane == 0) ? 0.f : Eb;
#pragma unroll
  for (int i = 0; i < 4; ++i) {
    carry[base + (size_t)i * D_DIM] = h;
    h = A[i] * h + Bv[i];
  }
}

// ---------------- final within-chunk scan + output ----------------

__global__ __launch_bounds__(128) void scan_pass3(const u32* __restrict__ av_buf,
                                                  const float4* __restrict__ carry,
                                                  float4* __restrict__ out) {
  const int c = blockIdx.x;
  const int b = blockIdx.y;
  const int d4 = threadIdx.x;
  float4 hh = carry[((size_t)(b * NC + c)) * 128 + d4];
  float h[4] = {hh.x, hh.y, hh.z, hh.w};
  size_t base = ((size_t)b * T_DIM + (size_t)c * LCH) * D_DIM + d4 * 4;
  for (int t = 0; t < LCH; ++t) {
    uint4 w = *reinterpret_cast<const uint4*>(av_buf + base);
    h[0] = bf2f(w.x & 0xffff) * h[0] + bf2f(w.x >> 16);
    h[1] = bf2f(w.y & 0xffff) * h[1] + bf2f(w.y >> 16);
    h[2] = bf2f(w.z & 0xffff) * h[2] + bf2f(w.z >> 16);
    h[3] = bf2f(w.w & 0xffff) * h[3] + bf2f(w.w >> 16);
    out[base >> 2] = make_float4(h[0], h[1], h[2], h[3]);
    base += D_DIM;
  }
}

// ---------------- launch ----------------

extern "C" void kernel_launch(void* const* d_in, const int* in_sizes, int n_in,
                              void* d_out, int out_size, void* d_ws, size_t ws_size,
                              hipStream_t stream) {
  const float* x = (const float*)d_in[0];   // [4,8192,512]
  const float* W = (const float*)d_in[1];   // [512,1024]
  float* out = (float*)d_out;               // [4,8192,512]

  char* ws = (char*)d_ws;
  u16*   xb     = (u16*)(ws + 0);             // 33,554,432
  u16*   wtp    = (u16*)(ws + 33554432);      //  1,048,576
  u32*   av_buf = (u32*)(ws + 34603008);      // 67,108,864 (a lo16 | v hi16)
  float* Asum   = (float*)(ws + 101711872);   //  2,097,152
  float* Bsum   = (float*)(ws + 103809024);   //  2,097,152
  float* carry  = (float*)(ws + 105906176);   //  2,097,152  (end 108,003,328)
  if (ws_size < 108003328ULL) return;

  convert_x<<<2048, 256, 0, stream>>>((const float4*)x, xb, (M_DIM * K_DIM) / 4);
  convert_wt<<<256, 256, 0, stream>>>(W, wtp);
  gemm_act<<<dim3(M_DIM / 256, D_DIM / 64), 512, 0, stream>>>(xb, wtp, av_buf, Asum, Bsum);
  scan_pass2<<<512, 256, 0, stream>>>(Asum, Bsum, carry);
  scan_pass3<<<dim3(NC, B_DIM), 128, 0, stream>>>(av_buf, (const float4*)carry, (float4*)out);
}